// Round 3
// baseline (362.879 us; speedup 1.0000x reference)
//
#include <hip/hip_runtime.h>

#define BB 16384
#define DD 4096
#define CC 10
#define NPAIR 90          // 10 classes x 9 offsets
#define MARGIN 0.1
#define NBLK (BB / 4)     // 4096 blocks, 1 row per wave

// d_ws layout:
//   [0, 32 KB)            : partial[4096] double   (written every call by tl_main)
//   [32 KB, 32 KB + 720)  : consts[90]   double    (written every call by tl_prep)
//   [64 KB, 64 KB+1.44 MB): diffs[90*4096] float   (written every call by tl_prep)

__global__ __launch_bounds__(256) void tl_prep(
        const float* __restrict__ anchors,
        float*  __restrict__ diffs,
        double* __restrict__ consts) {
    const int pair = blockIdx.x;          // 0..89
    const int c   = pair / 9;
    const int o   = pair % 9;
    const int neg = (c + 1 + o) % CC;

    const float4* t4 = (const float4*)anchors + (size_t)c   * (DD / 4);
    const float4* n4 = (const float4*)anchors + (size_t)neg * (DD / 4);
    float4* d4 = (float4*)diffs + (size_t)pair * (DD / 4);

    double acc = 0.0;
    for (int i = threadIdx.x; i < DD / 4; i += 256) {
        float4 t = t4[i];
        float4 n = n4[i];
        float4 d;
        d.x = t.x - n.x; d.y = t.y - n.y; d.z = t.z - n.z; d.w = t.w - n.w;
        d4[i] = d;
        acc += (double)t.x * t.x - (double)n.x * n.x;
        acc += (double)t.y * t.y - (double)n.y * n.y;
        acc += (double)t.z * t.z - (double)n.z * n.z;
        acc += (double)t.w * t.w - (double)n.w * n.w;
    }

    __shared__ double sh[256];
    sh[threadIdx.x] = acc;
    __syncthreads();
    #pragma unroll
    for (int stride = 128; stride > 0; stride >>= 1) {
        if (threadIdx.x < stride) sh[threadIdx.x] += sh[threadIdx.x + stride];
        __syncthreads();
    }
    if (threadIdx.x == 0) consts[pair] = sh[0];
}

__global__ __launch_bounds__(256) void tl_main(
        const float* __restrict__ pred,
        const int*   __restrict__ clss,
        const int*   __restrict__ neg_offset,
        const float* __restrict__ diffs,
        const double* __restrict__ consts,
        double* __restrict__ partial) {
    const int wave = threadIdx.x >> 6;   // 0..3
    const int lane = threadIdx.x & 63;
    const int row  = blockIdx.x * 4 + wave;

    const int cls  = clss[row];
    const int pair = cls * 9 + (neg_offset[row] % 9);

    const float4* p4 = (const float4*)pred  + (size_t)row  * (DD / 4);
    const float4* d4 = (const float4*)diffs + (size_t)pair * (DD / 4);

    // dot(p, t - n) in fp32; 2 streams, 16 iterations, 8 float4 live per 4 iters
    float s = 0.0f;
    #pragma unroll 4
    for (int i = 0; i < (DD / 4) / 64; ++i) {
        const int j = i * 64 + lane;
        float4 p = p4[j];
        float4 d = d4[j];
        s += p.x * d.x + p.y * d.y + p.z * d.z + p.w * d.w;
    }

    #pragma unroll
    for (int off = 32; off > 0; off >>= 1)
        s += __shfl_down(s, off, 64);

    __shared__ double wsum[4];
    if (lane == 0)
        wsum[wave] = consts[pair] - 2.0 * (double)s;   // row value = ||t||^2-||n||^2 - 2 p.(t-n)
    __syncthreads();

    if (threadIdx.x == 0)
        partial[blockIdx.x] = wsum[0] + wsum[1] + wsum[2] + wsum[3];
}

__global__ __launch_bounds__(256) void tl_reduce(
        const double* __restrict__ partial,
        float* __restrict__ out) {
    const int tid = threadIdx.x;
    double s = 0.0;
    #pragma unroll
    for (int i = 0; i < NBLK / 256; ++i)
        s += partial[i * 256 + tid];

    __shared__ double sh[256];
    sh[tid] = s;
    __syncthreads();
    #pragma unroll
    for (int stride = 128; stride > 0; stride >>= 1) {
        if (tid < stride) sh[tid] += sh[tid + stride];
        __syncthreads();
    }
    if (tid == 0)
        out[0] = (float)(MARGIN + sh[0] / ((double)BB * (double)DD));
}

extern "C" void kernel_launch(void* const* d_in, const int* in_sizes, int n_in,
                              void* d_out, int out_size, void* d_ws, size_t ws_size,
                              hipStream_t stream) {
    const float* pred       = (const float*)d_in[0];
    const float* anchors    = (const float*)d_in[1];
    const int*   clss       = (const int*)d_in[2];
    const int*   neg_offset = (const int*)d_in[3];
    float* out = (float*)d_out;

    char* ws = (char*)d_ws;
    double* partial = (double*)(ws);                 // 32 KB
    double* consts  = (double*)(ws + (32u << 10));   // 720 B
    float*  diffs   = (float*)(ws + (64u << 10));    // 1.44 MB

    hipLaunchKernelGGL(tl_prep, dim3(NPAIR), dim3(256), 0, stream,
                       anchors, diffs, consts);
    hipLaunchKernelGGL(tl_main, dim3(NBLK), dim3(256), 0, stream,
                       pred, clss, neg_offset, diffs, consts, partial);
    hipLaunchKernelGGL(tl_reduce, dim3(1), dim3(256), 0, stream, partial, out);
}